// Round 16
// baseline (231.768 us; speedup 1.0000x reference)
//
#include <hip/hip_runtime.h>
#include <hip/hip_bf16.h>

// Problem shapes (fixed):
//   hidden_states fp32 [WORLD=8][SEQ=2048][HID=4096]
//   gate_proj     fp32 [OUTD=8192][HID=4096]
//   out           fp32 [SEQ=2048][OUTD=8192]
// out = (sum_w hs[w]) @ W^T   (reduce-scatter sum commutes into the GEMM)
//
// r13 structure with 32x32x16 MFMA (2382-2495 TF ubench vs 2075 for 16x16x32):
// identical staging/schedule/swizzle; only fragment geometry + epilogue change.
// A/B-frag (analogy to verified 16x16x32): lane l -> row = l&31, k = (l>>5)*8+j.
// C/D (HW-verified m74/m101): col = lane&31, row = (r&3)+8*(r>>2)+4*(lane>>5).

#define HID   4096
#define SEQ   2048
#define WORLD 8
#define OUTD  8192

typedef __bf16 bf16x8  __attribute__((ext_vector_type(8)));
typedef short  s16x8   __attribute__((ext_vector_type(8)));
typedef float  f32x16  __attribute__((ext_vector_type(16)));
typedef float  f32x4   __attribute__((ext_vector_type(4)));

typedef const __attribute__((address_space(1))) void* gas1_ptr;
typedef __attribute__((address_space(3))) void*       las3_ptr;

static __device__ __forceinline__ unsigned short f2bf(float f) {
    union { float f; unsigned u; } v; v.f = f;
    unsigned u = v.u;
    u += 0x7fffu + ((u >> 16) & 1u);   // round-to-nearest-even
    return (unsigned short)(u >> 16);
}

// ------------- Kernel 1: fused (reduce over world + cast) | (cast W) -------------
#define RED_BLOCKS  2048
#define CONV_BLOCKS 4096
__global__ void prep_kernel(const float* __restrict__ hs,
                            const float* __restrict__ w,
                            unsigned short* __restrict__ xb,
                            unsigned short* __restrict__ wb) {
    if (blockIdx.x < RED_BLOCKS) {
        const int total4 = SEQ * HID / 4;
        const float4* h4 = (const float4*)hs;
        ushort4* o4 = (ushort4*)xb;
        for (int i = blockIdx.x * blockDim.x + threadIdx.x; i < total4;
             i += RED_BLOCKS * blockDim.x) {
            float4 s = h4[i];
            #pragma unroll
            for (int ww = 1; ww < WORLD; ++ww) {
                float4 t = h4[i + ww * total4];
                s.x += t.x; s.y += t.y; s.z += t.z; s.w += t.w;
            }
            ushort4 o;
            o.x = f2bf(s.x); o.y = f2bf(s.y); o.z = f2bf(s.z); o.w = f2bf(s.w);
            o4[i] = o;
        }
    } else {
        const int total4 = OUTD * HID / 4;
        const float4* w4 = (const float4*)w;
        ushort4* o4 = (ushort4*)wb;
        for (int i = (blockIdx.x - RED_BLOCKS) * blockDim.x + threadIdx.x;
             i < total4; i += CONV_BLOCKS * blockDim.x) {
            float4 s = w4[i];
            ushort4 o;
            o.x = f2bf(s.x); o.y = f2bf(s.y); o.z = f2bf(s.z); o.w = f2bf(s.w);
            o4[i] = o;
        }
    }
}

// ------ Kernel 2: 256x256 bf16 GEMM C = A*B^T, 32x32x16 MFMA, r7 schedule ------
// 8 waves (2Mx4N), 128x64 out/wave = 4x2 tiles of 32x32 (acc f32x16 x8 = 128 VGPR).
// LDS dbuf A/B [2][256][64] bf16 = 128 KiB. Swizzle: 16B slot' = slot ^ (row&7)
// on pre-swizzled global source + ds_read. Per K-tile (BK=64 = 4 k-steps of 16):
//   ph1: read vb (2n x 4ks = 8) + va=m0 (4); stage A(t+1)h1->q; lgkm0; MFMA m0
//   ph2: read vc=m1 (4); stage B(t+2)h0->p; lgkm0; MFMA m1
//   ph3: read va=m2 (4) + vd=m3 (4); stage B(t+2)h1->p; lgkm0; MFMA m2
//   ph4: stage A(t+2)h0->p; MFMA m3 (reg-only); vmcnt(6) | vmcnt(0) at tail.
// Safety identical to r7: all B reads of buf complete in ph1, all A reads by ph3.

#define BM 256
#define BN 256
#define BK 64
#define KSTEPS (HID / BK)   // 64

__global__ __launch_bounds__(512, 2)
void gemm_bt_kernel(const unsigned short* __restrict__ A,
                    const unsigned short* __restrict__ B,
                    float* __restrict__ C) {
    __shared__ __align__(16) unsigned short lsA[2][BM * BK];   // 64 KiB
    __shared__ __align__(16) unsigned short lsB[2][BN * BK];   // 64 KiB

    const int tid  = threadIdx.x;
    const int lane = tid & 63;
    const int wave = tid >> 6;
    const int wm   = wave >> 2;     // 0..1  -> rows wm*128
    const int wn   = wave & 3;      // 0..3  -> cols wn*64

    // 2D XCD tiling: xcd = bid&7 -> (gm,gn)=(xcd>>2, xcd&3); local 32 blocks = 4x8.
    const int bid   = blockIdx.x;
    const int xcd   = bid & 7;
    const int local = bid >> 3;               // 0..31
    const int bm = (xcd >> 2) * 4 + (local >> 3);   // 0..7
    const int bn = (xcd & 3) * 8 + (local & 7);     // 0..31

    // ---- staging geometry: lane -> (subrow = lane>>3, slot = lane&7) ----
    const int subrow = lane >> 3;
    const int slot   = lane & 7;
    const int scol   = (slot ^ subrow) * 8;   // pre-swizzled global col (elems)
    const unsigned short* aBase =
        A + (size_t)(bm * BM + wave * 8 + subrow) * HID + scol;
    const unsigned short* bBase =
        B + (size_t)(bn * BN + wave * 8 + subrow) * HID + scol;
    const int ldsW = wave * 8 * BK;           // wave-uniform LDS elem offset

#define ST_A(buf, ktv, l) __builtin_amdgcn_global_load_lds(                     \
        (gas1_ptr)(aBase + (size_t)(ktv) * BK + (size_t)(l) * 64 * HID),        \
        (las3_ptr)(&lsA[buf][(l) * 64 * BK + ldsW]), 16, 0, 0)
#define ST_B(buf, ktv, l) __builtin_amdgcn_global_load_lds(                     \
        (gas1_ptr)(bBase + (size_t)(ktv) * BK + (size_t)(l) * 64 * HID),        \
        (las3_ptr)(&lsB[buf][(l) * 64 * BK + ldsW]), 16, 0, 0)
#define STG_A(buf, ktv, h) do { ST_A(buf, ktv, 2*(h)); ST_A(buf, ktv, 2*(h)+1); } while (0)
#define STG_B(buf, ktv, h) do { ST_B(buf, ktv, 2*(h)); ST_B(buf, ktv, 2*(h)+1); } while (0)

    // ---- fragment geometry (32x32x16): lane -> row = lane&31, k = (lane>>5)*8 ----
    const int fr32  = lane & 31;
    const int fq2   = lane >> 5;               // 0..1
    const int axor  = fr32 & 7;                // (row & 7) for fragment rows
    const int k0 = ((0 + fq2) ^ axor) * 8;     // k-step 0: slot 2*0+fq2
    const int k1 = ((2 + fq2) ^ axor) * 8;     // k-step 1
    const int k2 = ((4 + fq2) ^ axor) * 8;     // k-step 2
    const int k3 = ((6 + fq2) ^ axor) * 8;     // k-step 3
    const int aRowB = (wm * 128 + fr32) * BK;
    const int bRowB = (wn * 64 + fr32) * BK;

#define RD_A(dst, P, mm, koff) dst = __builtin_bit_cast(bf16x8,                 \
        *(const s16x8*)&lsA[P][aRowB + (mm) * 32 * BK + (koff)])
#define RD_B(dst, P, nn, koff) dst = __builtin_bit_cast(bf16x8,                 \
        *(const s16x8*)&lsB[P][bRowB + (nn) * 32 * BK + (koff)])

#define RD_A4(ARR, P, mm) do { RD_A(ARR[0], P, mm, k0); RD_A(ARR[1], P, mm, k1); \
                               RD_A(ARR[2], P, mm, k2); RD_A(ARR[3], P, mm, k3); } while (0)

#define BARRIER() __builtin_amdgcn_s_barrier()
#define LGKM0()   asm volatile("s_waitcnt lgkmcnt(0)" ::: "memory")
#define VMC6()    asm volatile("s_waitcnt vmcnt(6)" ::: "memory")
#define VMC0()    asm volatile("s_waitcnt vmcnt(0)" ::: "memory")
#define PRIO1()   __builtin_amdgcn_s_setprio(1)
#define PRIO0()   __builtin_amdgcn_s_setprio(0)
#define SB()      __builtin_amdgcn_sched_barrier(0)

// 8-MFMA cluster: one 32-row m-tile (mi) x n0-1, all 4 k-steps
#define MFMA32(VAx, mi)                                                          \
    PRIO1();                                                                     \
    _Pragma("unroll")                                                            \
    for (int s = 0; s < 4; ++s)                                                  \
        _Pragma("unroll")                                                        \
        for (int n = 0; n < 2; ++n)                                              \
            acc[mi][n] = __builtin_amdgcn_mfma_f32_32x32x16_bf16(                \
                VAx[s], vb[n][s], acc[mi][n], 0, 0, 0);                          \
    PRIO0()

// One K-tile (buf P, other buf Q, tile index S). s1 = S+1<K, st = S+2<K.
#define TILE_SECTION(P, Q, S, s1, st)                                            \
    /* ---- ph1: all B (8) + A m0 (4) ---- */                                    \
    BARRIER(); SB();                                                             \
    RD_B(vb[0][0], P, 0, k0); RD_B(vb[0][1], P, 0, k1);                          \
    RD_B(vb[0][2], P, 0, k2); RD_B(vb[0][3], P, 0, k3);                          \
    RD_B(vb[1][0], P, 1, k0); RD_B(vb[1][1], P, 1, k1);                          \
    RD_B(vb[1][2], P, 1, k2); RD_B(vb[1][3], P, 1, k3);                          \
    RD_A4(va, P, 0);                                                             \
    if (s1) STG_A(Q, (S) + 1, 1);                                                \
    LGKM0(); SB();                                                               \
    MFMA32(va, 0);                                                               \
    SB();                                                                        \
    /* ---- ph2: A m1 (4) ---- */                                                \
    BARRIER(); SB();                                                             \
    RD_A4(vc, P, 1);                                                             \
    if (st) STG_B(P, (S) + 2, 0);                                                \
    LGKM0(); SB();                                                               \
    MFMA32(vc, 1);                                                               \
    SB();                                                                        \
    /* ---- ph3: A m2 + m3 (8) ---- */                                           \
    BARRIER(); SB();                                                             \
    RD_A4(va, P, 2);                                                             \
    RD_A4(vd, P, 3);                                                             \
    if (st) STG_B(P, (S) + 2, 1);                                                \
    LGKM0(); SB();                                                               \
    MFMA32(va, 2);                                                               \
    SB();                                                                        \
    /* ---- ph4: reg-only MFMA m3 ---- */                                        \
    BARRIER(); SB();                                                             \
    if (st) STG_A(P, (S) + 2, 0);                                                \
    MFMA32(vd, 3);                                                               \
    if (st) { VMC6(); } else { VMC0(); }                                         \
    SB()

    f32x16 acc[4][2] = {};
    bf16x8 va[4], vc[4], vd[4], vb[2][4];

    // ---- prologue: tile0 full (8), tile1 {Bh0,Bh1,Ah0} (6); A(1)h1 at ph1 ----
    STG_B(0, 0, 0); STG_B(0, 0, 1); STG_A(0, 0, 0); STG_A(0, 0, 1);
    STG_B(1, 1, 0); STG_B(1, 1, 1); STG_A(1, 1, 0);
    VMC6();          // tile0's 8 retired; tile1's 6 in flight

    #pragma unroll 1
    for (int t = 0; t < KSTEPS; t += 2) {
        const bool g1 = (t + 1 < KSTEPS), g2 = (t + 2 < KSTEPS), g3 = (t + 3 < KSTEPS);
        TILE_SECTION(0, 1, t,     g1, g2);
        TILE_SECTION(1, 0, t + 1, g2, g3);
    }

    // ---- epilogue: C/D 32x32: col = lane&31, row = (r&3)+8*(r>>2)+4*(lane>>5) ----
    const long crow0 = (long)bm * BM + wm * 128 + fq2 * 4;
    const long ccol0 = (long)bn * BN + wn * 64 + fr32;
    #pragma unroll
    for (int mi = 0; mi < 4; ++mi)
        #pragma unroll
        for (int n = 0; n < 2; ++n)
            #pragma unroll
            for (int r = 0; r < 16; ++r)
                C[(crow0 + mi * 32 + (r & 3) + 8 * (r >> 2)) * OUTD
                  + ccol0 + n * 32] = acc[mi][n][r];
}

extern "C" void kernel_launch(void* const* d_in, const int* in_sizes, int n_in,
                              void* d_out, int out_size, void* d_ws, size_t ws_size,
                              hipStream_t stream) {
    const float* hs = (const float*)d_in[0];
    const float* w  = (const float*)d_in[1];
    float* out = (float*)d_out;

    unsigned short* xb = (unsigned short*)d_ws;              // 16 MB  [SEQ][HID] bf16
    unsigned short* wb = xb + (size_t)SEQ * HID;             // 64 MB  [OUTD][HID] bf16

    hipLaunchKernelGGL(prep_kernel, dim3(RED_BLOCKS + CONV_BLOCKS), dim3(256),
                       0, stream, hs, w, xb, wb);
    hipLaunchKernelGGL(gemm_bt_kernel, dim3((SEQ / BM) * (OUTD / BN)), dim3(512),
                       0, stream, xb, wb, out);
}

// Round 17
// 220.183 us; speedup vs baseline: 1.0526x; 1.0526x over previous
//
#include <hip/hip_runtime.h>
#include <hip/hip_bf16.h>

// Problem shapes (fixed):
//   hidden_states fp32 [WORLD=8][SEQ=2048][HID=4096]
//   gate_proj     fp32 [OUTD=8192][HID=4096]
//   out           fp32 [SEQ=2048][OUTD=8192]
// out = (sum_w hs[w]) @ W^T   (reduce-scatter sum commutes into the GEMM)
//
// FINAL CONFIG (r7/r13, empirical best = 220.3-220.5 us over 17 rounds):
//   prep: fused reduce+cast | W cast, 6144 blocks, 88-90% HBM peak (roofline)
//   GEMM: 256x256 / 8 waves / BK=64 / 16x16x32 MFMA, one barrier per phase,
//         vmcnt(6) cadence, XOR-slot swizzle both-sides, 2D XCD tiling.
// Falsified alternatives (all measured): 8-phase counted (r4), 2-barrier
// pipelined (r5), sched_barrier pinned (r6), B-direct-global (r8, 2x worse),
// fused-W staging (r9/r11, neutral), no-drain (r10), 2 blocks/CU (r12, worse),
// grid-wide producer-consumer (r14, 16x worse), 32x32x16 MFMA (r16, worse).

#define HID   4096
#define SEQ   2048
#define WORLD 8
#define OUTD  8192

typedef __bf16 bf16x8 __attribute__((ext_vector_type(8)));
typedef short  s16x8  __attribute__((ext_vector_type(8)));
typedef float  f32x4  __attribute__((ext_vector_type(4)));

typedef const __attribute__((address_space(1))) void* gas1_ptr;
typedef __attribute__((address_space(3))) void*       las3_ptr;

static __device__ __forceinline__ unsigned short f2bf(float f) {
    union { float f; unsigned u; } v; v.f = f;
    unsigned u = v.u;
    u += 0x7fffu + ((u >> 16) & 1u);   // round-to-nearest-even
    return (unsigned short)(u >> 16);
}

// ------------- Kernel 1: fused (reduce over world + cast) | (cast W) -------------
#define RED_BLOCKS  2048
#define CONV_BLOCKS 4096
__global__ void prep_kernel(const float* __restrict__ hs,
                            const float* __restrict__ w,
                            unsigned short* __restrict__ xb,
                            unsigned short* __restrict__ wb) {
    if (blockIdx.x < RED_BLOCKS) {
        const int total4 = SEQ * HID / 4;
        const float4* h4 = (const float4*)hs;
        ushort4* o4 = (ushort4*)xb;
        for (int i = blockIdx.x * blockDim.x + threadIdx.x; i < total4;
             i += RED_BLOCKS * blockDim.x) {
            float4 s = h4[i];
            #pragma unroll
            for (int ww = 1; ww < WORLD; ++ww) {
                float4 t = h4[i + ww * total4];
                s.x += t.x; s.y += t.y; s.z += t.z; s.w += t.w;
            }
            ushort4 o;
            o.x = f2bf(s.x); o.y = f2bf(s.y); o.z = f2bf(s.z); o.w = f2bf(s.w);
            o4[i] = o;
        }
    } else {
        const int total4 = OUTD * HID / 4;
        const float4* w4 = (const float4*)w;
        ushort4* o4 = (ushort4*)wb;
        for (int i = (blockIdx.x - RED_BLOCKS) * blockDim.x + threadIdx.x;
             i < total4; i += CONV_BLOCKS * blockDim.x) {
            float4 s = w4[i];
            ushort4 o;
            o.x = f2bf(s.x); o.y = f2bf(s.y); o.z = f2bf(s.z); o.w = f2bf(s.w);
            o4[i] = o;
        }
    }
}

// ------ Kernel 2: 256x256 bf16 GEMM C = A*B^T, ONE barrier per phase ------
// 8 waves (2Mx4N), 128x64 out/wave. LDS dbuf A/B [2][256][64] bf16 = 128 KiB.
// Swizzle: 16B slot' = slot ^ (row&7) on pre-swizzled global source + ds_read.
// Phase = {BARRIER; ds_reads; stage; lgkm0; MFMA} — no end-of-phase barrier.
// Stage plan per tile t (buf p): ph1 A(t+1)h1->q, ph2 B(t+2)h0->p,
// ph3 B(t+2)h1->p, ph4 A(t+2)h0->p; next ph1 A(t+2)h1->p.
// vmcnt(6) at tile end (3 half-tiles in flight), vmcnt(0) when t+2>=K.

#define BM 256
#define BN 256
#define BK 64
#define KSTEPS (HID / BK)   // 64

__global__ __launch_bounds__(512, 2)
void gemm_bt_kernel(const unsigned short* __restrict__ A,
                    const unsigned short* __restrict__ B,
                    float* __restrict__ C) {
    __shared__ __align__(16) unsigned short lsA[2][BM * BK];   // 64 KiB
    __shared__ __align__(16) unsigned short lsB[2][BN * BK];   // 64 KiB

    const int tid  = threadIdx.x;
    const int lane = tid & 63;
    const int wave = tid >> 6;
    const int wm   = wave >> 2;     // 0..1  -> rows wm*128
    const int wn   = wave & 3;      // 0..3  -> cols wn*64

    // 2D XCD tiling: xcd = bid&7 -> (gm,gn)=(xcd>>2, xcd&3); local 32 blocks = 4x8.
    const int bid   = blockIdx.x;
    const int xcd   = bid & 7;
    const int local = bid >> 3;               // 0..31
    const int bm = (xcd >> 2) * 4 + (local >> 3);   // 0..7
    const int bn = (xcd & 3) * 8 + (local & 7);     // 0..31

    // ---- staging geometry: lane -> (subrow = lane>>3, slot = lane&7) ----
    const int subrow = lane >> 3;
    const int slot   = lane & 7;
    const int scol   = (slot ^ subrow) * 8;   // pre-swizzled global col (elems)
    const unsigned short* aBase =
        A + (size_t)(bm * BM + wave * 8 + subrow) * HID + scol;
    const unsigned short* bBase =
        B + (size_t)(bn * BN + wave * 8 + subrow) * HID + scol;
    const int ldsW = wave * 8 * BK;           // wave-uniform LDS elem offset

#define ST_A(buf, ktv, l) __builtin_amdgcn_global_load_lds(                     \
        (gas1_ptr)(aBase + (size_t)(ktv) * BK + (size_t)(l) * 64 * HID),        \
        (las3_ptr)(&lsA[buf][(l) * 64 * BK + ldsW]), 16, 0, 0)
#define ST_B(buf, ktv, l) __builtin_amdgcn_global_load_lds(                     \
        (gas1_ptr)(bBase + (size_t)(ktv) * BK + (size_t)(l) * 64 * HID),        \
        (las3_ptr)(&lsB[buf][(l) * 64 * BK + ldsW]), 16, 0, 0)
#define STG_A(buf, ktv, h) do { ST_A(buf, ktv, 2*(h)); ST_A(buf, ktv, 2*(h)+1); } while (0)
#define STG_B(buf, ktv, h) do { ST_B(buf, ktv, 2*(h)); ST_B(buf, ktv, 2*(h)+1); } while (0)

    // ---- fragment geometry ----
    const int fr    = lane & 15;
    const int fq    = lane >> 4;
    const int axor  = fr & 7;                  // (row & 7) for fragment rows
    const int koff0 = ((0 + fq) ^ axor) * 8;   // k-slice s=0
    const int koff1 = ((4 + fq) ^ axor) * 8;   // k-slice s=1
    const int aRowB = (wm * 128 + fr) * BK;
    const int bRowB = (wn * 64 + fr) * BK;

#define RD_A(dst, P, mm, koff) dst = __builtin_bit_cast(bf16x8,                 \
        *(const s16x8*)&lsA[P][aRowB + (mm) * 16 * BK + (koff)])
#define RD_B(dst, P, nn, koff) dst = __builtin_bit_cast(bf16x8,                 \
        *(const s16x8*)&lsB[P][bRowB + (nn) * 16 * BK + (koff)])

#define BARRIER() __builtin_amdgcn_s_barrier()
#define LGKM0()   asm volatile("s_waitcnt lgkmcnt(0)" ::: "memory")
#define VMC6()    asm volatile("s_waitcnt vmcnt(6)" ::: "memory")
#define VMC0()    asm volatile("s_waitcnt vmcnt(0)" ::: "memory")
#define PRIO1()   __builtin_amdgcn_s_setprio(1)
#define PRIO0()   __builtin_amdgcn_s_setprio(0)
#define SB()      __builtin_amdgcn_sched_barrier(0)

// 16-MFMA cluster: m-pair (mb, mb+1) x n0-3, both k-slices, from array VAx
#define MFMA16(VAx, mb)                                                          \
    PRIO1();                                                                     \
    _Pragma("unroll")                                                            \
    for (int s = 0; s < 2; ++s)                                                  \
        _Pragma("unroll")                                                        \
        for (int m = 0; m < 2; ++m)                                              \
            _Pragma("unroll")                                                    \
            for (int n = 0; n < 4; ++n)                                          \
                acc[(mb) + m][n] = __builtin_amdgcn_mfma_f32_16x16x32_bf16(      \
                    VAx[m][s], vb[n][s], acc[(mb) + m][n], 0, 0, 0);             \
    PRIO0()

// One K-tile (buf P, other buf Q, tile index S). s1 = S+1<K, st = S+2<K.
#define TILE_SECTION(P, Q, S, s1, st)                                            \
    /* ---- ph1 ---- */                                                          \
    BARRIER(); SB();                                                             \
    RD_B(vb[0][0], P, 0, koff0); RD_B(vb[0][1], P, 0, koff1);                    \
    RD_B(vb[1][0], P, 1, koff0); RD_B(vb[1][1], P, 1, koff1);                    \
    RD_B(vb[2][0], P, 2, koff0); RD_B(vb[2][1], P, 2, koff1);                    \
    RD_B(vb[3][0], P, 3, koff0); RD_B(vb[3][1], P, 3, koff1);                    \
    RD_A(va[0][0], P, 0, koff0); RD_A(va[0][1], P, 0, koff1);                    \
    RD_A(va[1][0], P, 1, koff0); RD_A(va[1][1], P, 1, koff1);                    \
    if (s1) STG_A(Q, (S) + 1, 1);                                                \
    LGKM0(); SB();                                                               \
    MFMA16(va, 0);                                                               \
    SB();                                                                        \
    /* ---- ph2 ---- */                                                          \
    BARRIER(); SB();                                                             \
    RD_A(vc[0][0], P, 2, koff0); RD_A(vc[0][1], P, 2, koff1);                    \
    RD_A(vc[1][0], P, 3, koff0); RD_A(vc[1][1], P, 3, koff1);                    \
    RD_A(va[0][0], P, 4, koff0); RD_A(va[0][1], P, 4, koff1);                    \
    RD_A(va[1][0], P, 5, koff0); RD_A(va[1][1], P, 5, koff1);                    \
    if (st) STG_B(P, (S) + 2, 0);                                                \
    LGKM0(); SB();                                                               \
    MFMA16(vc, 2);                                                               \
    SB();                                                                        \
    /* ---- ph3 ---- */                                                          \
    BARRIER(); SB();                                                             \
    RD_A(vd[0][0], P, 6, koff0); RD_A(vd[0][1], P, 6, koff1);                    \
    RD_A(vd[1][0], P, 7, koff0); RD_A(vd[1][1], P, 7, koff1);                    \
    if (st) STG_B(P, (S) + 2, 1);                                                \
    LGKM0(); SB();                                                               \
    MFMA16(va, 4);                                                               \
    SB();                                                                        \
    /* ---- ph4 ---- */                                                          \
    BARRIER(); SB();                                                             \
    if (st) STG_A(P, (S) + 2, 0);                                                \
    MFMA16(vd, 6);                                                               \
    if (st) { VMC6(); } else { VMC0(); }                                         \
    SB()

    f32x4 acc[8][4] = {};
    bf16x8 va[2][2], vc[2][2], vd[2][2], vb[4][2];

    // ---- prologue: tile0 full (8), tile1 {Bh0,Bh1,Ah0} (6); A(1)h1 at ph1 ----
    STG_B(0, 0, 0); STG_B(0, 0, 1); STG_A(0, 0, 0); STG_A(0, 0, 1);
    STG_B(1, 1, 0); STG_B(1, 1, 1); STG_A(1, 1, 0);
    VMC6();          // tile0's 8 retired; tile1's 6 in flight

    #pragma unroll 1
    for (int t = 0; t < KSTEPS; t += 2) {
        const bool g1 = (t + 1 < KSTEPS), g2 = (t + 2 < KSTEPS), g3 = (t + 3 < KSTEPS);
        TILE_SECTION(0, 1, t,     g1, g2);
        TILE_SECTION(1, 0, t + 1, g2, g3);
    }

    // ---- epilogue: C/D layout col = lane&15, row = (lane>>4)*4 + j ----
    const long crow0 = (long)bm * BM + wm * 128 + fq * 4;
    const long ccol0 = (long)bn * BN + wn * 64 + fr;
    #pragma unroll
    for (int m = 0; m < 8; ++m)
        #pragma unroll
        for (int n = 0; n < 4; ++n)
            #pragma unroll
            for (int j = 0; j < 4; ++j)
                C[(crow0 + m * 16 + j) * OUTD + ccol0 + n * 16] = acc[m][n][j];
}

extern "C" void kernel_launch(void* const* d_in, const int* in_sizes, int n_in,
                              void* d_out, int out_size, void* d_ws, size_t ws_size,
                              hipStream_t stream) {
    const float* hs = (const float*)d_in[0];
    const float* w  = (const float*)d_in[1];
    float* out = (float*)d_out;

    unsigned short* xb = (unsigned short*)d_ws;              // 16 MB  [SEQ][HID] bf16
    unsigned short* wb = xb + (size_t)SEQ * HID;             // 64 MB  [OUTD][HID] bf16

    hipLaunchKernelGGL(prep_kernel, dim3(RED_BLOCKS + CONV_BLOCKS), dim3(256),
                       0, stream, hs, w, xb, wb);
    hipLaunchKernelGGL(gemm_bt_kernel, dim3((SEQ / BM) * (OUTD / BN)), dim3(512),
                       0, stream, xb, wb, out);
}